// Round 4
// baseline (113.778 us; speedup 1.0000x reference)
//
#include <hip/hip_runtime.h>

// Problem: TemporalAttention_54322746359850
// Identity: softmax rows sum to 1 and einsum('TNS,BNH->BNH') contracts attn over
// BOTH T and S => y == 1024*v exactly; adjacency/QK/softmax are dead code.
//   att    = (1024*(h_pred@Wv + bv)) @ Wo + bo
//   gate   = sigmoid( silu([h_pred,h_prev]@gW1 + gb1) @ gW2 + gb2 )
//   h_corr = h_prev + gate*att
//   out    = h_corr + relu([h_corr,h_prev]@mW1 + mb1) @ mW2 + mb2
// Inputs f32, output f32.
//
// R13: R10/R11/R12 all = 67 MB weight broadcast and all = ~99.5-100.5 us
// (rounds/barriers/dtype/blocks all null). Only traffic ever moved the time
// (R8 slope ~0.15us/MB). This round halves traffic: ROWS=8 per block via TWO
// 4-row tiles sharing the SAME weight registers + bf16 ws weights:
//   128 blocks x 256 KB = 34 MB (vs 67).
// Structure = R12's 4 rounds; rounds 1-2 do 2 store/combine phases (one per
// tile) to keep part4 at 64 KB; rounds 3-4 pack both tiles in one phase.
// Per-output math order identical to R12 -> absmax 16.0.

#define HH 128
#define NROWS 1024
#define ROWSB 8     // rows per block (two tiles of 4)
#define RT 4        // rows per tile
#define NT 512      // threads per block (8 waves)
#define NG 16       // c-groups (8 K-rows each per 128-K)

// d_ws layout (uint32 units): packed bf16 row-pairs, elem[k2*128+j] = W[2k2][j] | W[2k2+1][j]<<16
#define WS_WV  0
#define WS_WO  8192
#define WS_GW1 16384
#define WS_GW2 32768
#define WS_MW1 40960
#define WS_MW2 57344

__device__ __forceinline__ unsigned int f2bf16(float f) {
    union { float f; unsigned int i; } x; x.f = f;
    unsigned int lsb = (x.i >> 16) & 1u;
    return (x.i + 0x7FFFu + lsb) >> 16;   // RNE
}

__global__ __launch_bounds__(256) void convert_weights(
    const float* __restrict__ Wv,  const float* __restrict__ Wo,
    const float* __restrict__ gW1, const float* __restrict__ gW2,
    const float* __restrict__ mW1, const float* __restrict__ mW2,
    unsigned int* __restrict__ dst)
{
    const int b = blockIdx.x;
    const float* src; unsigned int* d; int lb;
    if      (b < 32)  { src = Wv;  d = dst + WS_WV;  lb = b; }
    else if (b < 64)  { src = Wo;  d = dst + WS_WO;  lb = b - 32; }
    else if (b < 128) { src = gW1; d = dst + WS_GW1; lb = b - 64; }
    else if (b < 160) { src = gW2; d = dst + WS_GW2; lb = b - 128; }
    else if (b < 224) { src = mW1; d = dst + WS_MW1; lb = b - 160; }
    else              { src = mW2; d = dst + WS_MW2; lb = b - 224; }
    const int e  = lb * 256 + threadIdx.x;   // = k2*128 + j
    const int k2 = e >> 7, j = e & 127;
    const unsigned int lo = f2bf16(src[(2 * k2) * HH + j]);
    const unsigned int hi = f2bf16(src[(2 * k2 + 1) * HH + j]);
    d[e] = lo | (hi << 16);
}

__device__ __forceinline__ void fma4(float4& a, float s, const float4& w) {
    a.x += s * w.x; a.y += s * w.y; a.z += s * w.z; a.w += s * w.w;
}
__device__ __forceinline__ float4 bflo4(uint4 q) {
    return make_float4(__uint_as_float(q.x << 16), __uint_as_float(q.y << 16),
                       __uint_as_float(q.z << 16), __uint_as_float(q.w << 16));
}
__device__ __forceinline__ float4 bfhi4(uint4 q) {
    return make_float4(__uint_as_float(q.x & 0xffff0000u), __uint_as_float(q.y & 0xffff0000u),
                       __uint_as_float(q.z & 0xffff0000u), __uint_as_float(q.w & 0xffff0000u));
}

__global__ __launch_bounds__(NT) void temporal_attn_fused(
    const float* __restrict__ h_prev,
    const float* __restrict__ h_pred,
    const unsigned int* __restrict__ wbf,   // packed bf16 weights in d_ws
    const float* __restrict__ bv,  const float* __restrict__ bo,
    const float* __restrict__ gb1, const float* __restrict__ gb2,
    const float* __restrict__ mb1, const float* __restrict__ mb2,
    float* __restrict__ out)
{
    __shared__ __align__(16) float sPred[ROWSB][HH];
    __shared__ __align__(16) float sPrev[ROWSB][HH];
    __shared__ __align__(16) float sA[ROWSB][HH];     // a (scaled)
    __shared__ __align__(16) float sG1[ROWSB][HH];    // g1, then m1
    __shared__ __align__(16) float sCorr[ROWSB][HH];  // h_corr
    __shared__ float4 part4[NG][2][RT][HH / 4];       // 64 KB partials (2 outputs/phase)

    const int tid = threadIdx.x;
    const int jq  = tid & 31;                        // col-quad: cols 4*jq..4*jq+3
    const int cg  = ((tid >> 5) + blockIdx.x) & 15;  // rotated c-group: K-rows 8cg..8cg+7
    const int rr  = tid >> 7;                        // epilogue row 0..3 (tile-local)
    const int jj  = tid & (HH - 1);                  // epilogue col 0..127
    const int r0  = blockIdx.x * ROWSB;

    // ---- stage activations (coalesced, 2 rows/thread) + bias prefetch ----
    sPred[rr][jj]     = h_pred[(r0 + rr) * HH + jj];
    sPred[rr + 4][jj] = h_pred[(r0 + rr + 4) * HH + jj];
    sPrev[rr][jj]     = h_prev[(r0 + rr) * HH + jj];
    sPrev[rr + 4][jj] = h_prev[(r0 + rr + 4) * HH + jj];
    const float rbv  = bv[jj],  rbo  = bo[jj];
    const float rgb1 = gb1[jj], rgb2 = gb2[jj];
    const float rmb1 = mb1[jj], rmb2 = mb2[jj];
    __syncthreads();

    const float* pf = (const float*)part4;
    const int cbase = rr * HH + jj;                  // combine read base (floats)

    uint4 wa[12], wb[8];
    float4 acc[16];

    // load 4 uint4 = K-row-pairs 4cg..4cg+3 (+rp offset), cols 4jq..4jq+3
    #define LWB(dst, off, wsoff, rp) { \
        const uint4* B4 = (const uint4*)(wbf + (wsoff)); \
        _Pragma("unroll") for (int i = 0; i < 4; ++i) \
            dst[(off) + i] = B4[((rp) + 4 * cg + i) * 32 + jq]; }

    #define ZACC(n) { _Pragma("unroll") for (int r = 0; r < (n); ++r) \
        acc[r] = make_float4(0.f, 0.f, 0.f, 0.f); }

    // acc[aoff+r] += S[(ro)+r][8cg+2i]*lo + S[(ro)+r][8cg+2i+1]*hi over i=0..3
    #define FMAB(S, ro, wp, woff, aoff) { \
        _Pragma("unroll") for (int i = 0; i < 4; ++i) { \
            float4 wl = bflo4(wp[(woff) + i]); \
            float4 wh = bfhi4(wp[(woff) + i]); \
            _Pragma("unroll") for (int r = 0; r < RT; ++r) { \
                fma4(acc[(aoff) + r], S[(ro) + r][8 * cg + 2 * i],     wl); \
                fma4(acc[(aoff) + r], S[(ro) + r][8 * cg + 2 * i + 1], wh); } } }

    // store accs [a0..a0+3] -> slot 0, [a1..a1+3] -> slot 1, then barrier
    #define PSTORE2(a0, a1) { \
        _Pragma("unroll") for (int r = 0; r < RT; ++r) { \
            part4[cg][0][r][jq] = acc[(a0) + r]; \
            part4[cg][1][r][jq] = acc[(a1) + r]; } \
        __syncthreads(); }

    #define COMBINE2(d0, d1) \
        float d0 = 0.f, d1 = 0.f; \
        _Pragma("unroll") for (int g = 0; g < NG; ++g) { \
            d0 += pf[g * (2 * RT * HH) + cbase]; \
            d1 += pf[g * (2 * RT * HH) + (RT * HH) + cbase]; }

    // ---- round 1: a = 1024*(h_pred@Wv + bv)  ||  g1 = silu([h_pred,h_prev]@gW1 + gb1) ----
    // acc: 0-3 a(t0), 4-7 g1(t0), 8-11 a(t1), 12-15 g1(t1)
    LWB(wa, 0, WS_WV,  0);       // Wv
    LWB(wa, 4, WS_GW1, 0);       // gW1 rows 0..127  (x h_pred)
    LWB(wa, 8, WS_GW1, 64);      // gW1 rows 128..255 (x h_prev)
    LWB(wb, 0, WS_WO,  0);       // prefetch round 2
    LWB(wb, 4, WS_GW2, 0);
    ZACC(16);
    FMAB(sPred, 0, wa, 0, 0);
    FMAB(sPred, 0, wa, 4, 4);
    FMAB(sPrev, 0, wa, 8, 4);
    FMAB(sPred, 4, wa, 0, 8);
    FMAB(sPred, 4, wa, 4, 12);
    FMAB(sPrev, 4, wa, 8, 12);
    PSTORE2(0, 4);               // tile 0
    { COMBINE2(da, dg);
      sA[rr][jj] = 1024.f * (da + rbv);
      float x = dg + rgb1;
      sG1[rr][jj] = x / (1.f + __expf(-x)); }
    __syncthreads();
    PSTORE2(8, 12);              // tile 1
    { COMBINE2(da, dg);
      sA[rr + 4][jj] = 1024.f * (da + rbv);
      float x = dg + rgb1;
      sG1[rr + 4][jj] = x / (1.f + __expf(-x)); }
    __syncthreads();

    // ---- round 2: att = sA@Wo + bo  ||  glogit = sG1@gW2 + gb2 ; corr in-thread ----
    ZACC(16);
    FMAB(sA,  0, wb, 0, 0);
    FMAB(sG1, 0, wb, 4, 4);
    FMAB(sA,  4, wb, 0, 8);
    FMAB(sG1, 4, wb, 4, 12);
    LWB(wa, 0, WS_MW1, 0);       // prefetch round 3 (both halves of K=256)
    LWB(wa, 4, WS_MW1, 64);
    PSTORE2(0, 4);               // tile 0
    { COMBINE2(datt, dgl);
      float att  = datt + rbo;
      float gate = 1.f / (1.f + __expf(-(dgl + rgb2)));
      sCorr[rr][jj] = sPrev[rr][jj] + gate * att; }
    __syncthreads();
    PSTORE2(8, 12);              // tile 1
    { COMBINE2(datt, dgl);
      float att  = datt + rbo;
      float gate = 1.f / (1.f + __expf(-(dgl + rgb2)));
      sCorr[rr + 4][jj] = sPrev[rr + 4][jj] + gate * att; }
    __syncthreads();

    // ---- round 3: m1 = relu([h_corr,h_prev]@mW1 + mb1) -> sG1 (both tiles, one phase) ----
    ZACC(8);
    FMAB(sCorr, 0, wa, 0, 0);
    FMAB(sPrev, 0, wa, 4, 0);
    FMAB(sCorr, 4, wa, 0, 4);
    FMAB(sPrev, 4, wa, 4, 4);
    LWB(wb, 0, WS_MW2, 0);       // prefetch round 4
    PSTORE2(0, 4);               // slot0 = tile0, slot1 = tile1
    { COMBINE2(dm0, dm1);
      sG1[rr][jj]     = fmaxf(dm0 + rmb1, 0.f);
      sG1[rr + 4][jj] = fmaxf(dm1 + rmb1, 0.f); }
    __syncthreads();

    // ---- round 4: out = h_corr + m1@mW2 + mb2 (both tiles, one phase) ----
    ZACC(8);
    FMAB(sG1, 0, wb, 0, 0);
    FMAB(sG1, 4, wb, 0, 4);
    PSTORE2(0, 4);
    { COMBINE2(df0, df1);
      out[(r0 + rr) * HH + jj]     = sCorr[rr][jj]     + df0 + rmb2;
      out[(r0 + rr + 4) * HH + jj] = sCorr[rr + 4][jj] + df1 + rmb2; }
}

extern "C" void kernel_launch(void* const* d_in, const int* in_sizes, int n_in,
                              void* d_out, int out_size, void* d_ws, size_t ws_size,
                              hipStream_t stream) {
    // setup_inputs order:
    // 0 h_prev, 1 h_pred, 2 adj_rows, 3 adj_cols,
    // 4 Wq, 5 bq, 6 Wk, 7 bk, 8 Wv, 9 bv, 10 Wo, 11 bo,
    // 12 gW1, 13 gb1, 14 gW2, 15 gb2, 16 mW1, 17 mb1, 18 mW2, 19 mb2
    const float* h_prev = (const float*)d_in[0];
    const float* h_pred = (const float*)d_in[1];
    const float* Wv  = (const float*)d_in[8];
    const float* bv  = (const float*)d_in[9];
    const float* Wo  = (const float*)d_in[10];
    const float* bo  = (const float*)d_in[11];
    const float* gW1 = (const float*)d_in[12];
    const float* gb1 = (const float*)d_in[13];
    const float* gW2 = (const float*)d_in[14];
    const float* gb2 = (const float*)d_in[15];
    const float* mW1 = (const float*)d_in[16];
    const float* mb1 = (const float*)d_in[17];
    const float* mW2 = (const float*)d_in[18];
    const float* mb2 = (const float*)d_in[19];
    float* out = (float*)d_out;
    unsigned int* wbf = (unsigned int*)d_ws;

    hipLaunchKernelGGL(convert_weights, dim3(256), dim3(256), 0, stream,
                       Wv, Wo, gW1, gW2, mW1, mW2, wbf);

    hipLaunchKernelGGL(temporal_attn_fused, dim3(NROWS / ROWSB), dim3(NT), 0, stream,
                       h_prev, h_pred, wbf, bv, bo, gb1, gb2, mb1, mb2, out);
}

// Round 5
// 99.984 us; speedup vs baseline: 1.1380x; 1.1380x over previous
//
#include <hip/hip_runtime.h>

// Problem: TemporalAttention_54322746359850
// Identity: softmax rows sum to 1 and einsum('TNS,BNH->BNH') contracts attn over
// BOTH T and S => y == 1024*v exactly; adjacency/QK/softmax are dead code.
//   att    = (1024*(h_pred@Wv + bv)) @ Wo + bo
//   gate   = sigmoid( silu([h_pred,h_prev]@gW1 + gb1) @ gW2 + gb2 )
//   h_corr = h_prev + gate*att
//   out    = h_corr + relu([h_corr,h_prev]@mW1 + mb1) @ mW2 + mb2
// Inputs f32, output f32.
//
// R14: RESTORE of the best-measured kernel (R10 structure; 98.4us prior
// session, 99.4us round-0 rerun), undoing R13's grid-halving regression
// (+13.8us). Session evidence: iteration = ~80.5us unconditional 256MiB
// ws-poison fills (84% HBM peak) + ~12-15us harness restore-dispatch
// overhead + only ~4-6us our kernels. Round count (R12), dispatch count
// (R11), weight dtype (R11), and traffic (R11/R13: L2/L3 absorbs the
// broadcast - cold FETCH_SIZE 6MB << 34MB nominal) are all null at +-0.6us
// noise. Our kernels sit at the controllable floor.

#define HH 128
#define NROWS 1024
#define ROWS 4      // rows per block
#define NT 512      // threads per block (8 waves)
#define NG 16       // c-groups (8 K-rows each per 128-K)

// d_ws layout (uint32 units): packed bf16 row-pairs, elem[k2*128+j] = W[2k2][j] | W[2k2+1][j]<<16
#define WS_WV  0
#define WS_WO  8192
#define WS_GW1 16384
#define WS_GW2 32768
#define WS_MW1 40960
#define WS_MW2 57344

__device__ __forceinline__ unsigned int f2bf16(float f) {
    union { float f; unsigned int i; } x; x.f = f;
    unsigned int lsb = (x.i >> 16) & 1u;
    return (x.i + 0x7FFFu + lsb) >> 16;   // RNE
}

__global__ __launch_bounds__(256) void convert_weights(
    const float* __restrict__ Wv,  const float* __restrict__ Wo,
    const float* __restrict__ gW1, const float* __restrict__ gW2,
    const float* __restrict__ mW1, const float* __restrict__ mW2,
    unsigned int* __restrict__ dst)
{
    const int b = blockIdx.x;
    const float* src; unsigned int* d; int lb;
    if      (b < 32)  { src = Wv;  d = dst + WS_WV;  lb = b; }
    else if (b < 64)  { src = Wo;  d = dst + WS_WO;  lb = b - 32; }
    else if (b < 128) { src = gW1; d = dst + WS_GW1; lb = b - 64; }
    else if (b < 160) { src = gW2; d = dst + WS_GW2; lb = b - 128; }
    else if (b < 224) { src = mW1; d = dst + WS_MW1; lb = b - 160; }
    else              { src = mW2; d = dst + WS_MW2; lb = b - 224; }
    const int e  = lb * 256 + threadIdx.x;   // = k2*128 + j
    const int k2 = e >> 7, j = e & 127;
    const unsigned int lo = f2bf16(src[(2 * k2) * HH + j]);
    const unsigned int hi = f2bf16(src[(2 * k2 + 1) * HH + j]);
    d[e] = lo | (hi << 16);
}

__device__ __forceinline__ void fma4(float4& a, float s, const float4& w) {
    a.x += s * w.x; a.y += s * w.y; a.z += s * w.z; a.w += s * w.w;
}
__device__ __forceinline__ float4 bflo4(uint4 q) {
    return make_float4(__uint_as_float(q.x << 16), __uint_as_float(q.y << 16),
                       __uint_as_float(q.z << 16), __uint_as_float(q.w << 16));
}
__device__ __forceinline__ float4 bfhi4(uint4 q) {
    return make_float4(__uint_as_float(q.x & 0xffff0000u), __uint_as_float(q.y & 0xffff0000u),
                       __uint_as_float(q.z & 0xffff0000u), __uint_as_float(q.w & 0xffff0000u));
}

__global__ __launch_bounds__(NT) void temporal_attn_fused(
    const float* __restrict__ h_prev,
    const float* __restrict__ h_pred,
    const unsigned int* __restrict__ wbf,   // packed bf16 weights in d_ws
    const float* __restrict__ bv,  const float* __restrict__ bo,
    const float* __restrict__ gb1, const float* __restrict__ gb2,
    const float* __restrict__ mb1, const float* __restrict__ mb2,
    float* __restrict__ out)
{
    __shared__ __align__(16) float sPred[ROWS][HH];
    __shared__ __align__(16) float sPrev[ROWS][HH];
    __shared__ __align__(16) float sBuf[ROWS][HH];   // a, then g1, then m1
    __shared__ __align__(16) float sCorr[ROWS][HH];
    __shared__ __align__(16) float sAtt[ROWS][HH];
    __shared__ float4 part4[NG][ROWS][HH / 4];       // 32 KB partials

    const int tid = threadIdx.x;
    const int jq  = tid & 31;                        // col-quad: cols 4*jq..4*jq+3
    const int cg  = ((tid >> 5) + blockIdx.x) & 15;  // rotated c-group: K-rows 8cg..8cg+7
    const int rr  = tid >> 7;                        // epilogue row 0..3
    const int jj  = tid & (HH - 1);                  // epilogue col 0..127
    const int r0  = blockIdx.x * ROWS;

    // ---- stage activations (coalesced) + bias prefetch ----
    sPred[rr][jj] = h_pred[(r0 + rr) * HH + jj];
    sPrev[rr][jj] = h_prev[(r0 + rr) * HH + jj];
    const float rbv  = bv[jj],  rbo  = bo[jj];
    const float rgb1 = gb1[jj], rgb2 = gb2[jj];
    const float rmb1 = mb1[jj], rmb2 = mb2[jj];
    __syncthreads();

    const float* pf = (const float*)part4;
    const int cbase = rr * HH + jj;                  // combine read base (dwords)

    uint4 wa[8], wb[8];
    float4 acc[ROWS];

    // load 4 uint4 = K-row-pairs 4cg..4cg+3 (+rp offset), cols 4jq..4jq+3
    #define LWB(dst, off, wsoff, rp) { \
        const uint4* B4 = (const uint4*)(wbf + (wsoff)); \
        _Pragma("unroll") for (int i = 0; i < 4; ++i) \
            dst[(off) + i] = B4[((rp) + 4 * cg + i) * 32 + jq]; }

    #define ZACC() { _Pragma("unroll") for (int r = 0; r < ROWS; ++r) \
        acc[r] = make_float4(0.f, 0.f, 0.f, 0.f); }

    // acc += S[r][8cg+2i]*lo + S[r][8cg+2i+1]*hi over i=0..3
    #define FMAB(S, wp, woff) { \
        _Pragma("unroll") for (int i = 0; i < 4; ++i) { \
            float4 wl = bflo4(wp[(woff) + i]); \
            float4 wh = bfhi4(wp[(woff) + i]); \
            _Pragma("unroll") for (int r = 0; r < ROWS; ++r) { \
                fma4(acc[r], S[r][8 * cg + 2 * i],     wl); \
                fma4(acc[r], S[r][8 * cg + 2 * i + 1], wh); } } }

    #define PSTORE() { \
        _Pragma("unroll") for (int r = 0; r < ROWS; ++r) part4[cg][r][jq] = acc[r]; \
        __syncthreads(); }

    #define COMBINE(dotvar) \
        float dotvar = 0.f; \
        _Pragma("unroll") for (int g = 0; g < NG; ++g) dotvar += pf[g * (ROWS * HH) + cbase];

    // ---- step 1: a = 1024*(h_pred @ Wv + bv) -> sBuf ----
    LWB(wa, 0, WS_WV, 0);        // s1 weights
    LWB(wb, 0, WS_WO, 0);        // prefetch s2
    ZACC(); FMAB(sPred, wa, 0);
    LWB(wa, 0, WS_GW1, 0);       // prefetch s3 (both halves)
    LWB(wa, 4, WS_GW1, 64);
    PSTORE();
    { COMBINE(dot); sBuf[rr][jj] = 1024.f * (dot + rbv); }
    __syncthreads();

    // ---- step 2: att = a @ Wo + bo -> sAtt ----
    ZACC(); FMAB(sBuf, wb, 0);
    LWB(wb, 0, WS_GW2, 0);       // prefetch s4
    PSTORE();
    { COMBINE(dot); sAtt[rr][jj] = dot + rbo; }
    __syncthreads();

    // ---- step 3: g1 = silu([h_pred,h_prev] @ gW1 + gb1) -> sBuf ----
    ZACC(); FMAB(sPred, wa, 0); FMAB(sPrev, wa, 4);
    LWB(wa, 0, WS_MW1, 0);       // prefetch s5 (both halves)
    LWB(wa, 4, WS_MW1, 64);
    PSTORE();
    { COMBINE(dot);
      float x = dot + rgb1;
      sBuf[rr][jj] = x / (1.f + __expf(-x)); }
    __syncthreads();

    // ---- step 4: gate = sigmoid(g1 @ gW2 + gb2); h_corr = h_prev + gate*att ----
    ZACC(); FMAB(sBuf, wb, 0);
    LWB(wb, 0, WS_MW2, 0);       // prefetch s6
    PSTORE();
    { COMBINE(dot);
      float gate = 1.f / (1.f + __expf(-(dot + rgb2)));
      sCorr[rr][jj] = sPrev[rr][jj] + gate * sAtt[rr][jj]; }
    __syncthreads();

    // ---- step 5: m1 = relu([h_corr,h_prev] @ mW1 + mb1) -> sBuf ----
    ZACC(); FMAB(sCorr, wa, 0); FMAB(sPrev, wa, 4);
    PSTORE();
    { COMBINE(dot); sBuf[rr][jj] = fmaxf(dot + rmb1, 0.f); }
    __syncthreads();

    // ---- step 6: out = h_corr + m1 @ mW2 + mb2 ----
    ZACC(); FMAB(sBuf, wb, 0);
    PSTORE();
    { COMBINE(dot); out[(r0 + rr) * HH + jj] = sCorr[rr][jj] + dot + rmb2; }
}

extern "C" void kernel_launch(void* const* d_in, const int* in_sizes, int n_in,
                              void* d_out, int out_size, void* d_ws, size_t ws_size,
                              hipStream_t stream) {
    // setup_inputs order:
    // 0 h_prev, 1 h_pred, 2 adj_rows, 3 adj_cols,
    // 4 Wq, 5 bq, 6 Wk, 7 bk, 8 Wv, 9 bv, 10 Wo, 11 bo,
    // 12 gW1, 13 gb1, 14 gW2, 15 gb2, 16 mW1, 17 mb1, 18 mW2, 19 mb2
    const float* h_prev = (const float*)d_in[0];
    const float* h_pred = (const float*)d_in[1];
    const float* Wv  = (const float*)d_in[8];
    const float* bv  = (const float*)d_in[9];
    const float* Wo  = (const float*)d_in[10];
    const float* bo  = (const float*)d_in[11];
    const float* gW1 = (const float*)d_in[12];
    const float* gb1 = (const float*)d_in[13];
    const float* gW2 = (const float*)d_in[14];
    const float* gb2 = (const float*)d_in[15];
    const float* mW1 = (const float*)d_in[16];
    const float* mb1 = (const float*)d_in[17];
    const float* mW2 = (const float*)d_in[18];
    const float* mb2 = (const float*)d_in[19];
    float* out = (float*)d_out;
    unsigned int* wbf = (unsigned int*)d_ws;

    hipLaunchKernelGGL(convert_weights, dim3(256), dim3(256), 0, stream,
                       Wv, Wo, gW1, gW2, mW1, mW2, wbf);

    hipLaunchKernelGGL(temporal_attn_fused, dim3(NROWS / ROWS), dim3(NT), 0, stream,
                       h_prev, h_pred, wbf, bv, bo, gb1, gb2, mb1, mb2, out);
}